// Round 2
// baseline (188.143 us; speedup 1.0000x reference)
//
#include <hip/hip_runtime.h>
#include <hip/hip_bf16.h>

// Problem constants
#define B_    4
#define T_    4096
#define C_    512
#define H_    8
#define D_    64
#define KS_   9
#define PAD_  4
#define MTOT  (B_ * T_)          // 16384
#define PLANE (MTOT * C_)        // elements per q/k/v plane
#define WU    (C_ * C_ / 8)      // weight units of 8 elements

typedef __bf16 bf16_t;
typedef __bf16 bf16x8 __attribute__((ext_vector_type(8)));
typedef float  f32x4  __attribute__((ext_vector_type(4)));

// ---------------------------------------------------------------------------
// Weights fp32 -> bf16 (x is consumed as fp32 directly by gemm8p<0> now).
// ---------------------------------------------------------------------------
__global__ __launch_bounds__(256)
void conv_w(const float* __restrict__ Wq, const float* __restrict__ Wk,
            const float* __restrict__ Wv, const float* __restrict__ Wo,
            bf16_t* __restrict__ dst) {
  int i = blockIdx.x * 256 + threadIdx.x;       // 0 .. 4*WU-1
  int w = i >> 15;                              // WU = 1<<15
  const float* W = (w == 0) ? Wq : (w == 1) ? Wk : (w == 2) ? Wv : Wo;
  const float* s = W + (size_t)(i & (WU - 1)) * 8;
  float4 f0 = ((const float4*)s)[0];
  float4 f1 = ((const float4*)s)[1];
  bf16x8 o;
  o[0] = (bf16_t)f0.x; o[1] = (bf16_t)f0.y; o[2] = (bf16_t)f0.z; o[3] = (bf16_t)f0.w;
  o[4] = (bf16_t)f1.x; o[5] = (bf16_t)f1.y; o[6] = (bf16_t)f1.z; o[7] = (bf16_t)f1.w;
  ((bf16x8*)dst)[i] = o;
}

// ---------------------------------------------------------------------------
// Phase-split GEMM with ring-3 LDS and counted vmcnt (T1+T2+T3/T4+T5 stack).
//   C[m][n] = sum_k A[m][k] * Bw[n][k]   (+bias in epilogue)
// BM=256 x BN=128 tile, BK=64, 8 waves (2m x 4n), per-wave 128x32 output.
// MODE 0: A = x fp32 [MTOT][C]. A is REGISTER-staged (T14): tile kt issues
//   the 8 dwordx4 fp32 loads for kt+2, converts+ds_writes kt+1's regs into
//   slot (kt+1)%3 (readers of that slot finished two tiles ago). Compiler
//   auto-inserts the load->use vmcnt for the plain loads. B slabs for kt+2
//   go via global_load_lds into slot (kt+2)%3. Exit wait: 12 outstanding
//   (B(kt+1)2 oldest + A(kt+2)8 + B(kt+2)2) -> vmcnt(10) lands B(kt+1).
// MODE 1: A = y bf16 per-head planes; all staging via global_load_lds
//   (round-1 schedule, verified): 6 loads/tile, exit vmcnt(6).
// XOR chunk swizzle on both ds_write source-addressing and ds_read:
//   LDS slot ch of row r holds global k-chunk ch ^ (r&7).
// ---------------------------------------------------------------------------
#define BM   256
#define BN   128
#define BK   64
#define NKT  (C_ / BK)            // 8
#define ASL  (BM * BK)            // 16384 elems per A slot
#define BSL  (BN * BK)            // 8192
#define SLOT (ASL + BSL)          // 24576 elems = 48KB

#define GLD(srcp, off) __builtin_amdgcn_global_load_lds(                     \
    (const __attribute__((address_space(1))) unsigned int*)(srcp),           \
    (__attribute__((address_space(3))) unsigned int*)(&sm[off]), 16, 0, 0)

template<int MODE>
__global__ __launch_bounds__(512, 2)
void gemm8p(const void* __restrict__ Ap, const bf16_t* __restrict__ Bw,
            const float* __restrict__ b0, const float* __restrict__ b1,
            const float* __restrict__ b2, void* __restrict__ Outp) {
  __shared__ __align__(16) bf16_t sm[3 * SLOT];

  constexpr int GX  = (MODE == 0) ? (3 * C_ / BN) : (C_ / BN);  // 12 / 4
  constexpr int NWG = GX * (MTOT / BM);                         // 768 / 256
  constexpr int CPX = NWG / 8;                                  // NWG%8==0

  // XCD swizzle (m157): each XCD gets a contiguous chunk of logical tiles.
  const int ord = blockIdx.y * GX + blockIdx.x;
  const int lg  = (ord & 7) * CPX + (ord >> 3);
  const int n0  = (lg % GX) * BN;
  const int m0  = (lg / GX) * BM;

  const int tid  = threadIdx.x;
  const int lane = tid & 63;
  const int wave = tid >> 6;
  const int wm   = wave >> 2;          // 0..1  (A half)
  const int wn   = wave & 3;           // 0..3  (32-col slice)

  // Per-thread staging sources (inverse-swizzled global addresses).
  // A: 2048 16B-bf16 units (4/thread); B: 1024 units (2/thread).
  const float*  aF[4];   // MODE 0: fp32 source, 8 floats (32B) per unit
  const bf16_t* aB[4];   // MODE 1: bf16 source via global_load_lds
  const bf16_t* bSrc[2];
#pragma unroll
  for (int s = 0; s < 4; ++s) {
    int u = s * 512 + tid, r = u >> 3, ch = u & 7;
    int cs = (ch ^ (r & 7)) << 3;
    if constexpr (MODE == 0) {
      aF[s] = (const float*)Ap + (size_t)(m0 + r) * C_ + cs;
    } else {
      int bb = m0 >> 12, t0 = m0 & (T_ - 1);
      aB[s] = (const bf16_t*)Ap + ((size_t)bb * H_ * T_ + t0 + r) * D_ + cs;
    }
  }
#pragma unroll
  for (int s = 0; s < 2; ++s) {
    int u = s * 512 + tid, r = u >> 3, ch = u & 7;
    int cs = (ch ^ (r & 7)) << 3;
    bSrc[s] = Bw + (size_t)(n0 + r) * C_ + cs;
  }

  f32x4 areg[4][2];   // MODE 0 in-flight A staging (32 VGPR)
#define LDF4(p)   (((const f32x4*)(p))[0])
#define WRA(s, off) do {                                                     \
    bf16x8 wv_;                                                              \
    wv_[0] = (bf16_t)areg[s][0][0]; wv_[1] = (bf16_t)areg[s][0][1];          \
    wv_[2] = (bf16_t)areg[s][0][2]; wv_[3] = (bf16_t)areg[s][0][3];          \
    wv_[4] = (bf16_t)areg[s][1][0]; wv_[5] = (bf16_t)areg[s][1][1];          \
    wv_[6] = (bf16_t)areg[s][1][2]; wv_[7] = (bf16_t)areg[s][1][3];          \
    *(bf16x8*)&sm[(off) + ((s) * 512 + tid) * 8] = wv_;                      \
  } while (0)

  // --- Prologue: tile0 resident in slot0, tile1 staged/in-flight to slot1.
  if constexpr (MODE == 0) {
#pragma unroll
    for (int s = 0; s < 4; ++s) {
      areg[s][0] = LDF4(aF[s]);     areg[s][1] = LDF4(aF[s] + 4);
    }
#pragma unroll
    for (int s = 0; s < 4; ++s) WRA(s, 0);          // A0 -> slot0 (auto wait)
#pragma unroll
    for (int s = 0; s < 2; ++s) GLD(bSrc[s], ASL + (s * 512 + tid) * 8);
#pragma unroll
    for (int s = 0; s < 4; ++s) {                    // A1 -> regs (in flight)
      areg[s][0] = LDF4(aF[s] + BK); areg[s][1] = LDF4(aF[s] + BK + 4);
    }
#pragma unroll
    for (int s = 0; s < 2; ++s) GLD(bSrc[s] + BK, SLOT + ASL + (s * 512 + tid) * 8);
    // outstanding: B0(2, oldest) A1(8) B1(2) -> land B0 only
    asm volatile("s_waitcnt vmcnt(10)" ::: "memory");
  } else {
    constexpr size_t AS = (size_t)T_ * D_;           // head stride
#pragma unroll
    for (int s = 0; s < 4; ++s) GLD(aB[s], (s * 512 + tid) * 8);
#pragma unroll
    for (int s = 0; s < 2; ++s) GLD(bSrc[s], ASL + (s * 512 + tid) * 8);
#pragma unroll
    for (int s = 0; s < 4; ++s) GLD(aB[s] + AS, SLOT + (s * 512 + tid) * 8);
#pragma unroll
    for (int s = 0; s < 2; ++s) GLD(bSrc[s] + BK, SLOT + ASL + (s * 512 + tid) * 8);
    asm volatile("s_waitcnt vmcnt(6)" ::: "memory");
  }
  asm volatile("s_waitcnt lgkmcnt(0)" ::: "memory"); // A0 ds_writes drained
  __builtin_amdgcn_s_barrier();

  f32x4 acc[8][2] = {};
  const int lr  = lane & 15;                       // fragment row
  const int lq  = lane >> 4;                       // k-group
  const int co0 = ((0 + lq) ^ (lane & 7)) << 3;    // swizzled chunk, kk=0
  const int co1 = ((4 + lq) ^ (lane & 7)) << 3;    // kk=1

  int rsl = 0;                                     // read slot = kt%3
  for (int kt = 0; kt < NKT; ++kt) {
    const bf16_t* arow = &sm[rsl * SLOT + (wm * 128 + lr) * 64];
    const bf16_t* brow = &sm[rsl * SLOT + ASL + (wn * 32 + lr) * 64];
    const int wA = ((rsl == 2) ? 0 : rsl + 1) * SLOT;   // slot (kt+1)%3
    const int wB = ((rsl == 0) ? 2 : rsl - 1) * SLOT;   // slot (kt+2)%3
    const bool w1 = (kt + 1 < NKT);                     // write A(kt+1)
    const bool st = (kt + 2 < NKT);                     // stage kt+2
    const size_t ka = (size_t)(kt + 2) * BK;

    bf16x8 af[4][2], bfr[2][2];

    // ---- phase 0: read A(mh=0)+B; A-stage half 1; MFMA mh0 x nf0
#pragma unroll
    for (int i = 0; i < 4; ++i) {
      af[i][0] = *(const bf16x8*)(arow + i * 1024 + co0);
      af[i][1] = *(const bf16x8*)(arow + i * 1024 + co1);
    }
#pragma unroll
    for (int nf = 0; nf < 2; ++nf) {
      bfr[nf][0] = *(const bf16x8*)(brow + nf * 1024 + co0);
      bfr[nf][1] = *(const bf16x8*)(brow + nf * 1024 + co1);
    }
    if constexpr (MODE == 0) {
      if (w1) { WRA(0, wA); WRA(1, wA); }              // auto vmcnt wait
      if (st) {
        areg[0][0] = LDF4(aF[0] + ka); areg[0][1] = LDF4(aF[0] + ka + 4);
        areg[1][0] = LDF4(aF[1] + ka); areg[1][1] = LDF4(aF[1] + ka + 4);
      }
    } else {
      constexpr size_t AS = (size_t)T_ * D_;
      if (st) {
        GLD(aB[0] + (size_t)(kt + 2) * AS, wB + (0 * 512 + tid) * 8);
        GLD(aB[1] + (size_t)(kt + 2) * AS, wB + (1 * 512 + tid) * 8);
      }
    }
    __builtin_amdgcn_sched_barrier(0);
    __builtin_amdgcn_s_barrier();
    asm volatile("s_waitcnt lgkmcnt(0)" ::: "memory");
    __builtin_amdgcn_sched_barrier(0);
    __builtin_amdgcn_s_setprio(1);
#pragma unroll
    for (int i = 0; i < 4; ++i)
#pragma unroll
      for (int kk = 0; kk < 2; ++kk)
        acc[i][0] = __builtin_amdgcn_mfma_f32_16x16x32_bf16(
            af[i][kk], bfr[0][kk], acc[i][0], 0, 0, 0);
    __builtin_amdgcn_s_setprio(0);
    __builtin_amdgcn_sched_barrier(0);
    __builtin_amdgcn_s_barrier();

    // ---- phase 1: A-stage half 2; MFMA mh0 x nf1 (regs from phase 0)
    if constexpr (MODE == 0) {
      if (w1) { WRA(2, wA); WRA(3, wA); }
      if (st) {
        areg[2][0] = LDF4(aF[2] + ka); areg[2][1] = LDF4(aF[2] + ka + 4);
        areg[3][0] = LDF4(aF[3] + ka); areg[3][1] = LDF4(aF[3] + ka + 4);
      }
    } else {
      constexpr size_t AS = (size_t)T_ * D_;
      if (st) {
        GLD(aB[2] + (size_t)(kt + 2) * AS, wB + (2 * 512 + tid) * 8);
        GLD(aB[3] + (size_t)(kt + 2) * AS, wB + (3 * 512 + tid) * 8);
      }
    }
    __builtin_amdgcn_sched_barrier(0);
    __builtin_amdgcn_s_barrier();
    __builtin_amdgcn_s_setprio(1);
#pragma unroll
    for (int i = 0; i < 4; ++i)
#pragma unroll
      for (int kk = 0; kk < 2; ++kk)
        acc[i][1] = __builtin_amdgcn_mfma_f32_16x16x32_bf16(
            af[i][kk], bfr[1][kk], acc[i][1], 0, 0, 0);
    __builtin_amdgcn_s_setprio(0);
    __builtin_amdgcn_sched_barrier(0);
    __builtin_amdgcn_s_barrier();

    // ---- phase 2: read A(mh=1); stage B(kt+2); MFMA mh1 x nf0
#pragma unroll
    for (int i = 0; i < 4; ++i) {
      af[i][0] = *(const bf16x8*)(arow + 4096 + i * 1024 + co0);
      af[i][1] = *(const bf16x8*)(arow + 4096 + i * 1024 + co1);
    }
    if (st) {
      GLD(bSrc[0] + ka, wB + ASL + (0 * 512 + tid) * 8);
      GLD(bSrc[1] + ka, wB + ASL + (1 * 512 + tid) * 8);
    }
    __builtin_amdgcn_sched_barrier(0);
    __builtin_amdgcn_s_barrier();
    asm volatile("s_waitcnt lgkmcnt(0)" ::: "memory");
    __builtin_amdgcn_sched_barrier(0);
    __builtin_amdgcn_s_setprio(1);
#pragma unroll
    for (int i = 0; i < 4; ++i)
#pragma unroll
      for (int kk = 0; kk < 2; ++kk)
        acc[4 + i][0] = __builtin_amdgcn_mfma_f32_16x16x32_bf16(
            af[i][kk], bfr[0][kk], acc[4 + i][0], 0, 0, 0);
    __builtin_amdgcn_s_setprio(0);
    __builtin_amdgcn_sched_barrier(0);
    __builtin_amdgcn_s_barrier();

    // ---- phase 3: MFMA mh1 x nf1; K-tile boundary (counted vmcnt, T4)
    __builtin_amdgcn_s_setprio(1);
#pragma unroll
    for (int i = 0; i < 4; ++i)
#pragma unroll
      for (int kk = 0; kk < 2; ++kk)
        acc[4 + i][1] = __builtin_amdgcn_mfma_f32_16x16x32_bf16(
            af[i][kk], bfr[1][kk], acc[4 + i][1], 0, 0, 0);
    __builtin_amdgcn_s_setprio(0);
    __builtin_amdgcn_sched_barrier(0);
    if constexpr (MODE == 0) {
      // outstanding: B(kt+1)2 oldest + A(kt+2)8 + B(kt+2)2
      if (kt < NKT - 2)       asm volatile("s_waitcnt vmcnt(10)" ::: "memory");
      else if (kt == NKT - 2) asm volatile("s_waitcnt vmcnt(0)" ::: "memory");
    } else {
      if (kt < NKT - 2)       asm volatile("s_waitcnt vmcnt(6)" ::: "memory");
      else if (kt == NKT - 2) asm volatile("s_waitcnt vmcnt(0)" ::: "memory");
    }
    __builtin_amdgcn_s_barrier();
    rsl = (rsl == 2) ? 0 : rsl + 1;
  }

  // Epilogue. C/D layout: col = lane&15, row = (lane>>4)*4 + reg  [m89]
  const int rq = (lane >> 4) << 2;
  if constexpr (MODE == 0) {
    const int z  = n0 >> 9;                        // BN=128 | 512 -> z uniform
    const float* bias = (z == 0) ? b0 : (z == 1) ? b1 : b2;
    const int bb = m0 >> 12;
    const int t0 = m0 & (T_ - 1);
    bf16_t* plane = (bf16_t*)Outp + (size_t)z * PLANE;
#pragma unroll
    for (int nf = 0; nf < 2; ++nf) {
      const int cc  = (n0 & (C_ - 1)) + wn * 32 + nf * 16 + lr;
      const int hh  = cc >> 6, dd = cc & 63;
      const float bvv = bias[cc];
      bf16_t* hb = plane + ((size_t)(bb * H_ + hh) * T_) * D_ + dd;
#pragma unroll
      for (int f = 0; f < 8; ++f)
#pragma unroll
        for (int r = 0; r < 4; ++r) {
          const int t = t0 + wm * 128 + f * 16 + rq + r;
          hb[(size_t)t * D_] = (bf16_t)(acc[f][nf][r] + bvv);
        }
    }
  } else {
    float* outp = (float*)Outp;
#pragma unroll
    for (int nf = 0; nf < 2; ++nf) {
      const int n = n0 + wn * 32 + nf * 16 + lr;
      const float bvv = b0[n];
#pragma unroll
      for (int f = 0; f < 8; ++f)
#pragma unroll
        for (int r = 0; r < 4; ++r) {
          const int m = m0 + wm * 128 + f * 16 + rq + r;
          outp[(size_t)m * C_ + n] = acc[f][nf][r] + bvv;
        }
    }
  }
}

// ---------------------------------------------------------------------------
// Neighborhood attention: 8 threads per (b,h,t), d-octet each; width-8
// shfl_xor score reduce; per-head plane I/O (fully coalesced). Unchanged.
// ---------------------------------------------------------------------------
__global__ __launch_bounds__(256)
void attn_kernel(const bf16_t* __restrict__ qkv, bf16_t* __restrict__ y) {
  const int tid  = threadIdx.x;
  const int sub  = tid & 7;
  const int tl   = tid >> 3;
  const int t    = blockIdx.x * 32 + tl;
  const int h    = blockIdx.y;
  const int b    = blockIdx.z;

  const size_t pl = (size_t)(b * H_ + h) * T_ * D_;
  const bf16_t* q = qkv + pl;
  const bf16_t* k = qkv + (size_t)PLANE + pl;
  const bf16_t* v = qkv + (size_t)2 * PLANE + pl;
  const int c = sub * 8;

  int tj[KS_];
#pragma unroll
  for (int j = 0; j < KS_; ++j) {
    int tt = t - PAD_ + j;
    tj[j] = tt < 0 ? 0 : (tt >= T_ ? T_ - 1 : tt);
  }

  bf16x8 q8 = *(const bf16x8*)(q + (size_t)t * D_ + c);
  float qf[8];
#pragma unroll
  for (int e = 0; e < 8; ++e) qf[e] = (float)q8[e];

  float s[KS_];
#pragma unroll
  for (int j = 0; j < KS_; ++j) {
    bf16x8 k8 = *(const bf16x8*)(k + (size_t)tj[j] * D_ + c);
    float d0 = 0.f;
#pragma unroll
    for (int e = 0; e < 8; ++e) d0 += qf[e] * (float)k8[e];
    s[j] = d0;
  }

#pragma unroll
  for (int m = 1; m < 8; m <<= 1)
#pragma unroll
    for (int j = 0; j < KS_; ++j) s[j] += __shfl_xor(s[j], m, 8);

  float mx = s[0];
#pragma unroll
  for (int j = 1; j < KS_; ++j) mx = fmaxf(mx, s[j]);
  float w[KS_], sum = 0.f;
#pragma unroll
  for (int j = 0; j < KS_; ++j) {
    w[j] = __expf((s[j] - mx) * 0.125f);   // scale = 1/sqrt(64)
    sum += w[j];
  }
  const float inv = 1.f / sum;
#pragma unroll
  for (int j = 0; j < KS_; ++j) w[j] *= inv;

  float o[8] = {0.f, 0.f, 0.f, 0.f, 0.f, 0.f, 0.f, 0.f};
#pragma unroll
  for (int j = 0; j < KS_; ++j) {
    bf16x8 v8 = *(const bf16x8*)(v + (size_t)tj[j] * D_ + c);
#pragma unroll
    for (int e = 0; e < 8; ++e) o[e] += w[j] * (float)v8[e];
  }
  bf16x8 o8;
#pragma unroll
  for (int e = 0; e < 8; ++e) o8[e] = (bf16_t)o[e];
  *(bf16x8*)(y + pl + (size_t)t * D_ + c) = o8;
}

// ---------------------------------------------------------------------------
extern "C" void kernel_launch(void* const* d_in, const int* in_sizes, int n_in,
                              void* d_out, int out_size, void* d_ws, size_t ws_size,
                              hipStream_t stream) {
  const float* x  = (const float*)d_in[0];
  const float* Wq = (const float*)d_in[1];
  const float* bq = (const float*)d_in[2];
  const float* Wk = (const float*)d_in[3];
  const float* bk = (const float*)d_in[4];
  const float* Wv = (const float*)d_in[5];
  const float* bv = (const float*)d_in[6];
  const float* Wo = (const float*)d_in[7];
  const float* bo = (const float*)d_in[8];
  float* out = (float*)d_out;

  // Workspace: Wb 2MB | qkv 48MB | y 16MB  = 66 MB
  bf16_t* Wb  = (bf16_t*)d_ws;
  bf16_t* qkv = Wb + (size_t)4 * C_ * C_;
  bf16_t* y   = qkv + (size_t)3 * PLANE;

  conv_w<<<4 * WU / 256, 256, 0, stream>>>(Wq, Wk, Wv, Wo, Wb);
  gemm8p<0><<<dim3(3 * C_ / BN, MTOT / BM), 512, 0, stream>>>(
      x, Wb, bq, bk, bv, qkv);
  attn_kernel<<<dim3(T_ / 32, H_, B_), 256, 0, stream>>>(qkv, y);
  gemm8p<1><<<dim3(C_ / BN, MTOT / BM), 512, 0, stream>>>(
      y, Wb + (size_t)3 * C_ * C_, bo, nullptr, nullptr, out);
}

// Round 3
// 166.424 us; speedup vs baseline: 1.1305x; 1.1305x over previous
//
#include <hip/hip_runtime.h>
#include <hip/hip_bf16.h>

// Problem constants
#define B_    4
#define T_    4096
#define C_    512
#define H_    8
#define D_    64
#define KS_   9
#define PAD_  4
#define MTOT  (B_ * T_)          // 16384
#define PLANE (MTOT * C_)        // elements per q/k/v plane
#define WU    (C_ * C_ / 8)      // weight units of 8 elements

typedef __bf16 bf16_t;
typedef __bf16 bf16x8 __attribute__((ext_vector_type(8)));
typedef float  f32x4  __attribute__((ext_vector_type(4)));

// ---------------------------------------------------------------------------
// fp32 -> bf16 for the 4 weight matrices AND x (GEMM A consumed via
// global_load_lds which cannot convert). 4*WU + PLANE/8 units, 8 elem each.
// ---------------------------------------------------------------------------
__global__ __launch_bounds__(256)
void conv_all(const float* __restrict__ Wq, const float* __restrict__ Wk,
              const float* __restrict__ Wv, const float* __restrict__ Wo,
              const float* __restrict__ x,
              bf16_t* __restrict__ Wb, bf16_t* __restrict__ xb) {
  int i = blockIdx.x * 256 + threadIdx.x;
  const float* src;
  bf16_t* dst;
  if (i < 4 * WU) {                        // WU = 1<<15
    int w = i >> 15;
    const float* W = (w == 0) ? Wq : (w == 1) ? Wk : (w == 2) ? Wv : Wo;
    src = W + (size_t)(i & (WU - 1)) * 8;
    dst = Wb + (size_t)i * 8;
  } else {
    size_t j = (size_t)(i - 4 * WU);
    src = x + j * 8;
    dst = xb + j * 8;
  }
  float4 f0 = ((const float4*)src)[0];
  float4 f1 = ((const float4*)src)[1];
  bf16x8 o;
  o[0] = (bf16_t)f0.x; o[1] = (bf16_t)f0.y; o[2] = (bf16_t)f0.z; o[3] = (bf16_t)f0.w;
  o[4] = (bf16_t)f1.x; o[5] = (bf16_t)f1.y; o[6] = (bf16_t)f1.z; o[7] = (bf16_t)f1.w;
  *(bf16x8*)dst = o;
}

// ---------------------------------------------------------------------------
// Phase-split GEMM, ring-3 LDS, counted vmcnt (T1+T2+T3/T4+T5), r1 staging.
//   C[m][n] = sum_k A[m][k] * Bw[n][k]   (+bias in epilogue)
// BM=256 x BN=128, BK=64, 8 waves as 4m x 2n -> per-wave 64x64 output.
//   (r1 used 2m x 4n = 128x32/wave: 20 ds_read_b128/wave/tile, phases
//    {12,0,8,0}. 4m x 2n: 16 reads {8,4,4,0} -> -20% LDS-pipe traffic and
//    evenly fed phases. acc[4][4], af[4][2]+bfr[4][2] all held = 128 VGPR.)
// Quadrant phases per K-tile (8 MFMA each):
//   P0: read af[0,1],bfr[0,1]; GLD A01(kt+2); MFMA m01 x n01
//   P1: read bfr[2,3];         GLD A23(kt+2); MFMA m01 x n23
//   P2: read af[2,3];          GLD B01(kt+2); MFMA m23 x n01
//   P3:                        boundary;      MFMA m23 x n23
// Ring-3 slots; boundary waits vmcnt(6) (kt+2's 6 loads stay in flight),
// vmcnt(0) only at the last staged boundary.
// XOR chunk swizzle: LDS slot ch of row r holds global k-chunk ch^(r&7)
// (inverse-swizzled global source, linear gload_lds dest, swizzled ds_read).
// MODE 0: A = xb bf16 [MTOT][C], Bw = Wq|Wk|Wv packed, out -> qkv planes.
// MODE 1: A = y bf16 per-head planes (K-tile kt == head kt), out fp32.
// ---------------------------------------------------------------------------
#define BM   256
#define BN   128
#define BK   64
#define NKT  (C_ / BK)            // 8
#define ASL  (BM * BK)            // 16384 elems per A slot
#define BSL  (BN * BK)            // 8192
#define SLOT (ASL + BSL)          // 24576 elems = 48KB

#define GLD(srcp, off) __builtin_amdgcn_global_load_lds(                     \
    (const __attribute__((address_space(1))) unsigned int*)(srcp),           \
    (__attribute__((address_space(3))) unsigned int*)(&sm[off]), 16, 0, 0)

template<int MODE>
__global__ __launch_bounds__(512, 2)
void gemm8p(const bf16_t* __restrict__ A, const bf16_t* __restrict__ Bw,
            const float* __restrict__ b0, const float* __restrict__ b1,
            const float* __restrict__ b2, void* __restrict__ Outp) {
  __shared__ __align__(16) bf16_t sm[3 * SLOT];

  constexpr int GX  = (MODE == 0) ? (3 * C_ / BN) : (C_ / BN);  // 12 / 4
  constexpr int NWG = GX * (MTOT / BM);                         // 768 / 256
  constexpr int CPX = NWG / 8;                                  // NWG%8==0

  // XCD swizzle (m157): consecutive logical n-blocks (sharing an A panel)
  // land on one XCD's L2.
  const int ord = blockIdx.y * GX + blockIdx.x;
  const int lg  = (ord & 7) * CPX + (ord >> 3);
  const int n0  = (lg % GX) * BN;
  const int m0  = (lg / GX) * BM;

  const int tid  = threadIdx.x;
  const int lane = tid & 63;
  const int wave = tid >> 6;
  const int wm   = wave >> 1;          // 0..3  (64-row slice)
  const int wn   = wave & 1;           // 0..1  (64-col slice)

  // Per-thread staging sources (inverse-swizzled global addresses).
  // A: 2048 16B units (4/thread); B: 1024 units (2/thread).
  const bf16_t* aSrc[4];
  const bf16_t* bSrc[2];
#pragma unroll
  for (int s = 0; s < 4; ++s) {
    int u = s * 512 + tid, r = u >> 3, ch = u & 7;
    int cs = (ch ^ (r & 7)) << 3;
    if constexpr (MODE == 0) {
      aSrc[s] = A + (size_t)(m0 + r) * C_ + cs;
    } else {
      int bb = m0 >> 12, t0 = m0 & (T_ - 1);
      aSrc[s] = A + ((size_t)bb * H_ * T_ + t0 + r) * D_ + cs;  // head 0 base
    }
  }
#pragma unroll
  for (int s = 0; s < 2; ++s) {
    int u = s * 512 + tid, r = u >> 3, ch = u & 7;
    int cs = (ch ^ (r & 7)) << 3;
    bSrc[s] = Bw + (size_t)(n0 + r) * C_ + cs;
  }
  constexpr size_t ASTEP = (MODE == 0) ? (size_t)BK : (size_t)T_ * D_;

  // Prologue: kt0 -> slot0, kt1 -> slot1; wait kt0 only (vmcnt 6: kt1 in flight).
#pragma unroll
  for (int s = 0; s < 4; ++s) GLD(aSrc[s], (s * 512 + tid) * 8);
#pragma unroll
  for (int s = 0; s < 2; ++s) GLD(bSrc[s], ASL + (s * 512 + tid) * 8);
#pragma unroll
  for (int s = 0; s < 4; ++s) GLD(aSrc[s] + ASTEP, SLOT + (s * 512 + tid) * 8);
#pragma unroll
  for (int s = 0; s < 2; ++s) GLD(bSrc[s] + BK, SLOT + ASL + (s * 512 + tid) * 8);
  asm volatile("s_waitcnt vmcnt(6)" ::: "memory");
  __builtin_amdgcn_s_barrier();

  f32x4 acc[4][4] = {};
  const int lr  = lane & 15;                       // fragment row
  const int lq  = lane >> 4;                       // k-group
  const int co0 = ((0 + lq) ^ (lane & 7)) << 3;    // swizzled chunk, kk=0
  const int co1 = ((4 + lq) ^ (lane & 7)) << 3;    // kk=1

  int rsl = 0;                                     // read slot = kt%3
  for (int kt = 0; kt < NKT; ++kt) {
    const bf16_t* arow = &sm[rsl * SLOT + (wm * 64 + lr) * 64];
    const bf16_t* brow = &sm[rsl * SLOT + ASL + (wn * 64 + lr) * 64];
    const int  wof = ((rsl == 0) ? 2 : rsl - 1) * SLOT;   // slot (kt+2)%3
    const bool st  = (kt + 2 < NKT);
    const size_t ka = (size_t)(kt + 2) * ASTEP;
    const size_t kb = (size_t)(kt + 2) * BK;

    bf16x8 af[4][2], bfr[4][2];

    // ---- P0: read af[0,1] + bfr[0,1]; GLD A units 0,1; MFMA m01 x n01
#pragma unroll
    for (int i = 0; i < 2; ++i) {
      af[i][0]  = *(const bf16x8*)(arow + i * 1024 + co0);
      af[i][1]  = *(const bf16x8*)(arow + i * 1024 + co1);
      bfr[i][0] = *(const bf16x8*)(brow + i * 1024 + co0);
      bfr[i][1] = *(const bf16x8*)(brow + i * 1024 + co1);
    }
    if (st) {
      GLD(aSrc[0] + ka, wof + (0 * 512 + tid) * 8);
      GLD(aSrc[1] + ka, wof + (1 * 512 + tid) * 8);
    }
    __builtin_amdgcn_sched_barrier(0);
    __builtin_amdgcn_s_barrier();
    asm volatile("s_waitcnt lgkmcnt(0)" ::: "memory");
    __builtin_amdgcn_sched_barrier(0);
    __builtin_amdgcn_s_setprio(1);
#pragma unroll
    for (int i = 0; i < 2; ++i)
#pragma unroll
      for (int j = 0; j < 2; ++j)
#pragma unroll
        for (int kk = 0; kk < 2; ++kk)
          acc[i][j] = __builtin_amdgcn_mfma_f32_16x16x32_bf16(
              af[i][kk], bfr[j][kk], acc[i][j], 0, 0, 0);
    __builtin_amdgcn_s_setprio(0);
    __builtin_amdgcn_sched_barrier(0);
    __builtin_amdgcn_s_barrier();

    // ---- P1: read bfr[2,3]; GLD A units 2,3; MFMA m01 x n23
#pragma unroll
    for (int j = 2; j < 4; ++j) {
      bfr[j][0] = *(const bf16x8*)(brow + j * 1024 + co0);
      bfr[j][1] = *(const bf16x8*)(brow + j * 1024 + co1);
    }
    if (st) {
      GLD(aSrc[2] + ka, wof + (2 * 512 + tid) * 8);
      GLD(aSrc[3] + ka, wof + (3 * 512 + tid) * 8);
    }
    __builtin_amdgcn_sched_barrier(0);
    __builtin_amdgcn_s_barrier();
    asm volatile("s_waitcnt lgkmcnt(0)" ::: "memory");
    __builtin_amdgcn_sched_barrier(0);
    __builtin_amdgcn_s_setprio(1);
#pragma unroll
    for (int i = 0; i < 2; ++i)
#pragma unroll
      for (int j = 2; j < 4; ++j)
#pragma unroll
        for (int kk = 0; kk < 2; ++kk)
          acc[i][j] = __builtin_amdgcn_mfma_f32_16x16x32_bf16(
              af[i][kk], bfr[j][kk], acc[i][j], 0, 0, 0);
    __builtin_amdgcn_s_setprio(0);
    __builtin_amdgcn_sched_barrier(0);
    __builtin_amdgcn_s_barrier();

    // ---- P2: read af[2,3]; GLD B units 0,1; MFMA m23 x n01
#pragma unroll
    for (int i = 2; i < 4; ++i) {
      af[i][0] = *(const bf16x8*)(arow + i * 1024 + co0);
      af[i][1] = *(const bf16x8*)(arow + i * 1024 + co1);
    }
    if (st) {
      GLD(bSrc[0] + kb, wof + ASL + (0 * 512 + tid) * 8);
      GLD(bSrc[1] + kb, wof + ASL + (1 * 512 + tid) * 8);
    }
    __builtin_amdgcn_sched_barrier(0);
    __builtin_amdgcn_s_barrier();
    asm volatile("s_waitcnt lgkmcnt(0)" ::: "memory");
    __builtin_amdgcn_sched_barrier(0);
    __builtin_amdgcn_s_setprio(1);
#pragma unroll
    for (int i = 2; i < 4; ++i)
#pragma unroll
      for (int j = 0; j < 2; ++j)
#pragma unroll
        for (int kk = 0; kk < 2; ++kk)
          acc[i][j] = __builtin_amdgcn_mfma_f32_16x16x32_bf16(
              af[i][kk], bfr[j][kk], acc[i][j], 0, 0, 0);
    __builtin_amdgcn_s_setprio(0);
    __builtin_amdgcn_sched_barrier(0);
    __builtin_amdgcn_s_barrier();

    // ---- P3: MFMA m23 x n23; K-tile boundary (counted vmcnt, T4)
    __builtin_amdgcn_s_setprio(1);
#pragma unroll
    for (int i = 2; i < 4; ++i)
#pragma unroll
      for (int j = 2; j < 4; ++j)
#pragma unroll
        for (int kk = 0; kk < 2; ++kk)
          acc[i][j] = __builtin_amdgcn_mfma_f32_16x16x32_bf16(
              af[i][kk], bfr[j][kk], acc[i][j], 0, 0, 0);
    __builtin_amdgcn_s_setprio(0);
    __builtin_amdgcn_sched_barrier(0);
    if (kt < NKT - 2)       asm volatile("s_waitcnt vmcnt(6)" ::: "memory");
    else if (kt == NKT - 2) asm volatile("s_waitcnt vmcnt(0)" ::: "memory");
    __builtin_amdgcn_s_barrier();
    rsl = (rsl == 2) ? 0 : rsl + 1;
  }

  // Epilogue. C/D layout: col = lane&15, row = (lane>>4)*4 + reg  [m89]
  const int cn = lane & 15;
  const int rq = (lane >> 4) << 2;
  if constexpr (MODE == 0) {
    const int z  = n0 >> 9;                        // BN=128 | 512 -> z uniform
    const float* bias = (z == 0) ? b0 : (z == 1) ? b1 : b2;
    const int bb = m0 >> 12;
    const int t0 = m0 & (T_ - 1);
    bf16_t* plane = (bf16_t*)Outp + (size_t)z * PLANE;
#pragma unroll
    for (int j = 0; j < 4; ++j) {
      const int cc  = (n0 & (C_ - 1)) + wn * 64 + j * 16 + cn;
      const int hh  = cc >> 6, dd = cc & 63;
      const float bvv = bias[cc];
      bf16_t* hb = plane + ((size_t)(bb * H_ + hh) * T_) * D_ + dd;
#pragma unroll
      for (int i = 0; i < 4; ++i)
#pragma unroll
        for (int r = 0; r < 4; ++r) {
          const int t = t0 + wm * 64 + i * 16 + rq + r;
          hb[(size_t)t * D_] = (bf16_t)(acc[i][j][r] + bvv);
        }
    }
  } else {
    float* outp = (float*)Outp;
#pragma unroll
    for (int j = 0; j < 4; ++j) {
      const int n = n0 + wn * 64 + j * 16 + cn;
      const float bvv = b0[n];
#pragma unroll
      for (int i = 0; i < 4; ++i)
#pragma unroll
        for (int r = 0; r < 4; ++r) {
          const int m = m0 + wm * 64 + i * 16 + rq + r;
          outp[(size_t)m * C_ + n] = acc[i][j][r] + bvv;
        }
    }
  }
}

// ---------------------------------------------------------------------------
// Neighborhood attention: 8 threads per (b,h,t), d-octet each; width-8
// shfl_xor score reduce; per-head plane I/O (fully coalesced). Unchanged.
// ---------------------------------------------------------------------------
__global__ __launch_bounds__(256)
void attn_kernel(const bf16_t* __restrict__ qkv, bf16_t* __restrict__ y) {
  const int tid  = threadIdx.x;
  const int sub  = tid & 7;
  const int tl   = tid >> 3;
  const int t    = blockIdx.x * 32 + tl;
  const int h    = blockIdx.y;
  const int b    = blockIdx.z;

  const size_t pl = (size_t)(b * H_ + h) * T_ * D_;
  const bf16_t* q = qkv + pl;
  const bf16_t* k = qkv + (size_t)PLANE + pl;
  const bf16_t* v = qkv + (size_t)2 * PLANE + pl;
  const int c = sub * 8;

  int tj[KS_];
#pragma unroll
  for (int j = 0; j < KS_; ++j) {
    int tt = t - PAD_ + j;
    tj[j] = tt < 0 ? 0 : (tt >= T_ ? T_ - 1 : tt);
  }

  bf16x8 q8 = *(const bf16x8*)(q + (size_t)t * D_ + c);
  float qf[8];
#pragma unroll
  for (int e = 0; e < 8; ++e) qf[e] = (float)q8[e];

  float s[KS_];
#pragma unroll
  for (int j = 0; j < KS_; ++j) {
    bf16x8 k8 = *(const bf16x8*)(k + (size_t)tj[j] * D_ + c);
    float d0 = 0.f;
#pragma unroll
    for (int e = 0; e < 8; ++e) d0 += qf[e] * (float)k8[e];
    s[j] = d0;
  }

#pragma unroll
  for (int m = 1; m < 8; m <<= 1)
#pragma unroll
    for (int j = 0; j < KS_; ++j) s[j] += __shfl_xor(s[j], m, 8);

  float mx = s[0];
#pragma unroll
  for (int j = 1; j < KS_; ++j) mx = fmaxf(mx, s[j]);
  float w[KS_], sum = 0.f;
#pragma unroll
  for (int j = 0; j < KS_; ++j) {
    w[j] = __expf((s[j] - mx) * 0.125f);   // scale = 1/sqrt(64)
    sum += w[j];
  }
  const float inv = 1.f / sum;
#pragma unroll
  for (int j = 0; j < KS_; ++j) w[j] *= inv;

  float o[8] = {0.f, 0.f, 0.f, 0.f, 0.f, 0.f, 0.f, 0.f};
#pragma unroll
  for (int j = 0; j < KS_; ++j) {
    bf16x8 v8 = *(const bf16x8*)(v + (size_t)tj[j] * D_ + c);
#pragma unroll
    for (int e = 0; e < 8; ++e) o[e] += w[j] * (float)v8[e];
  }
  bf16x8 o8;
#pragma unroll
  for (int e = 0; e < 8; ++e) o8[e] = (bf16_t)o[e];
  *(bf16x8*)(y + pl + (size_t)t * D_ + c) = o8;
}

// ---------------------------------------------------------------------------
extern "C" void kernel_launch(void* const* d_in, const int* in_sizes, int n_in,
                              void* d_out, int out_size, void* d_ws, size_t ws_size,
                              hipStream_t stream) {
  const float* x  = (const float*)d_in[0];
  const float* Wq = (const float*)d_in[1];
  const float* bq = (const float*)d_in[2];
  const float* Wk = (const float*)d_in[3];
  const float* bk = (const float*)d_in[4];
  const float* Wv = (const float*)d_in[5];
  const float* bv = (const float*)d_in[6];
  const float* Wo = (const float*)d_in[7];
  const float* bo = (const float*)d_in[8];
  float* out = (float*)d_out;

  // Workspace: Wb 2MB | xb 16.8MB | qkv 50.3MB  (y aliases xb: xb is dead
  // once gemm8p<0> completes; attn writes y, gemm8p<1> reads it). ~69MB.
  bf16_t* Wb  = (bf16_t*)d_ws;
  bf16_t* xb  = Wb + (size_t)4 * C_ * C_;
  bf16_t* qkv = xb + (size_t)PLANE;
  bf16_t* y   = xb;

  conv_all<<<(4 * WU + PLANE / 8) / 256, 256, 0, stream>>>(Wq, Wk, Wv, Wo, x, Wb, xb);
  gemm8p<0><<<dim3(3 * C_ / BN, MTOT / BM), 512, 0, stream>>>(
      xb, Wb, bq, bk, bv, qkv);
  attn_kernel<<<dim3(T_ / 32, H_, B_), 256, 0, stream>>>(qkv, y);
  gemm8p<1><<<dim3(C_ / BN, MTOT / BM), 512, 0, stream>>>(
      y, Wb + (size_t)3 * C_ * C_, bo, nullptr, nullptr, out);
}